// Round 1
// baseline (249.915 us; speedup 1.0000x reference)
//
#include <hip/hip_runtime.h>

#define LSEQ 200
#define KCAP 4
#define NVOC 100000

// ---------------------------------------------------------------------------
// Kernel 1: P = (E with row 0 zeroed) @ S, P: (NVOC, 64) in workspace.
// v2: no LDS in the inner loop. Lane d holds S[:,d] in 64 VGPRs; the E row is
// wave-uniform (readfirstlane) so it compiles to s_load through the scalar
// cache. One coalesced 256B store per row per wave. VALU-bound ~10 us.
// ---------------------------------------------------------------------------
__global__ __launch_bounds__(256) void precompute_P(
    const float* __restrict__ E, const float* __restrict__ S,
    float* __restrict__ P)
{
    const int lane = threadIdx.x & 63;
    float s[64];
    #pragma unroll
    for (int e = 0; e < 64; e++) s[e] = S[e * 64 + lane];   // coalesced, L2-hot

    const int gw = (int)((blockIdx.x * blockDim.x + threadIdx.x) >> 6);
    const int nw = (int)((gridDim.x * blockDim.x) >> 6);
    for (int v = gw; v < NVOC; v += nw) {
        const int vu = __builtin_amdgcn_readfirstlane(v);   // force SGPR -> s_load
        const float* __restrict__ er = E + (size_t)vu * 64;
        float acc = 0.f;
        #pragma unroll
        for (int e = 0; e < 64; e++) acc = fmaf(er[e], s[e], acc);  // same e-order as v1: bit-identical
        P[(size_t)vu * 64 + lane] = (vu == 0) ? 0.f : acc;  // padding_idx=0
    }
}

// ---------------------------------------------------------------------------
// Kernel 2: one batch row per block (256 threads = 4 waves).
// v2: hisPl (52 KB LDS) is gone. Phase B keeps the register copy hp[50]
// (wave = 50 l's, lane = d). Phase D re-reads its P row from global
// (L2/L3-hot, float4 x16 per thread). LDS ~17 KB -> 5 blocks/CU
// (__launch_bounds__(256,5), VGPR cap 102 vs 88 used in v1).
// ---------------------------------------------------------------------------
__global__ __launch_bounds__(256, 5) void mind_row(
    const int*   __restrict__ his, const float* __restrict__ P,
    const float* __restrict__ B0,  const float* __restrict__ W1,
    const float* __restrict__ b1,  const float* __restrict__ W2,
    const float* __restrict__ b2,  float* __restrict__ out)
{
    __shared__ __align__(16) float W4[LSEQ * 4];       // W4[l*4+k]
    __shared__ __align__(16) float Bm[KCAP * LSEQ];    // Bm[k*200+l]
    __shared__ __align__(16) float caps4[64 * 4];      // caps4[d*4+k]
    __shared__ __align__(16) float part[4 * 4 * 64];   // part[q*256 + k*64 + d]
    __shared__ __align__(16) float h4[256 * 4];        // MLP hidden, h4[f*4+k]
    __shared__ float bigneg[LSEQ];
    __shared__ int   idxs[LSEQ];

    const int b    = blockIdx.x;
    const int tid  = threadIdx.x;
    const int lane = tid & 63;
    const int wv   = tid >> 6;

    for (int l = tid; l < LSEQ; l += 256) {
        int id = his[b * LSEQ + l];
        idxs[l]   = id;
        bigneg[l] = (id != 0) ? 0.f : -1e30f;
    }
    for (int t = tid; t < KCAP * LSEQ; t += 256) Bm[t] = B0[t];
    __syncthreads();

    // Gather: thread covers l in [wv*50, wv*50+50), column d = lane.
    // Registers only — no LDS copy needed anymore.
    float hp[50];
    #pragma unroll
    for (int i = 0; i < 50; i++) {
        int l = wv * 50 + i;
        hp[i] = P[idxs[l] * 64 + lane];       // 256B coalesced per wave
    }
    // no barrier needed: phase A only reads Bm/bigneg (synced above)

    for (int r = 0; r < 3; r++) {
        // A: masked softmax over l, capsule k = wv (one wave per capsule)
        {
            const float* Bk = Bm + wv * LSEQ;
            float x0 = Bk[lane]       + bigneg[lane];
            float x1 = Bk[lane + 64]  + bigneg[lane + 64];
            float x2 = Bk[lane + 128] + bigneg[lane + 128];
            float x3 = (lane < 8) ? (Bk[lane + 192] + bigneg[lane + 192]) : -3.0e38f;
            float m = fmaxf(fmaxf(x0, x1), fmaxf(x2, x3));
            #pragma unroll
            for (int off = 32; off; off >>= 1) m = fmaxf(m, __shfl_xor(m, off, 64));
            float e0 = __expf(x0 - m), e1 = __expf(x1 - m), e2 = __expf(x2 - m);
            float e3 = (lane < 8) ? __expf(x3 - m) : 0.f;
            float ssum = e0 + e1 + e2 + e3;
            #pragma unroll
            for (int off = 32; off; off >>= 1) ssum += __shfl_xor(ssum, off, 64);
            float inv = 1.f / ssum;
            W4[lane * 4 + wv]         = e0 * inv;
            W4[(lane + 64) * 4 + wv]  = e1 * inv;
            W4[(lane + 128) * 4 + wv] = e2 * inv;
            if (lane < 8) W4[(lane + 192) * 4 + wv] = e3 * inv;
        }
        __syncthreads();

        // B: caps partials from register-resident hisP (LDS: broadcasts only)
        {
            float a0 = 0, a1 = 0, a2 = 0, a3 = 0;
            #pragma unroll
            for (int i = 0; i < 50; i++) {
                int l = wv * 50 + i;
                float4 w = *(const float4*)(W4 + l * 4);   // broadcast b128
                float  v = hp[i];
                a0 = fmaf(w.x, v, a0);
                a1 = fmaf(w.y, v, a1);
                a2 = fmaf(w.z, v, a2);
                a3 = fmaf(w.w, v, a3);
            }
            part[wv * 256 + lane]       = a0;
            part[wv * 256 + 64 + lane]  = a1;
            part[wv * 256 + 128 + lane] = a2;
            part[wv * 256 + 192 + lane] = a3;
        }
        __syncthreads();

        // C: reduce partials + squash; thread = (k = wv, d = lane)
        {
            float c = part[wv * 64 + lane]       + part[256 + wv * 64 + lane]
                    + part[512 + wv * 64 + lane] + part[768 + wv * 64 + lane];
            float n2 = c * c;
            #pragma unroll
            for (int off = 32; off; off >>= 1) n2 += __shfl_xor(n2, off, 64);
            float n  = sqrtf(n2);
            float sc = n2 / ((1.f + n2) * n + 1e-9f);
            c *= sc;
            caps4[lane * 4 + wv] = c;
        }
        __syncthreads();

        if (r < 2) {
            // D: B[k][l] += caps[k] . hisP[l]  (thread per l).
            // hisP row re-read from global P: the block just gathered these
            // exact rows, so they are L1/L2/L3-hot. d-order ascending ->
            // bit-identical sum to the old LDS version.
            if (tid < LSEQ) {
                const float4* __restrict__ rowp = (const float4*)(P + idxs[tid] * 64);
                float d0 = 0, d1 = 0, d2 = 0, d3 = 0;
                #pragma unroll
                for (int j = 0; j < 16; j++) {
                    float4 v = rowp[j];
                    {
                        float4 c = *(const float4*)(caps4 + (j * 4 + 0) * 4);
                        d0 = fmaf(c.x, v.x, d0); d1 = fmaf(c.y, v.x, d1);
                        d2 = fmaf(c.z, v.x, d2); d3 = fmaf(c.w, v.x, d3);
                    }
                    {
                        float4 c = *(const float4*)(caps4 + (j * 4 + 1) * 4);
                        d0 = fmaf(c.x, v.y, d0); d1 = fmaf(c.y, v.y, d1);
                        d2 = fmaf(c.z, v.y, d2); d3 = fmaf(c.w, v.y, d3);
                    }
                    {
                        float4 c = *(const float4*)(caps4 + (j * 4 + 2) * 4);
                        d0 = fmaf(c.x, v.z, d0); d1 = fmaf(c.y, v.z, d1);
                        d2 = fmaf(c.z, v.z, d2); d3 = fmaf(c.w, v.z, d3);
                    }
                    {
                        float4 c = *(const float4*)(caps4 + (j * 4 + 3) * 4);
                        d0 = fmaf(c.x, v.w, d0); d1 = fmaf(c.y, v.w, d1);
                        d2 = fmaf(c.z, v.w, d2); d3 = fmaf(c.w, v.w, d3);
                    }
                }
                Bm[tid]       += d0;
                Bm[200 + tid] += d1;
                Bm[400 + tid] += d2;
                Bm[600 + tid] += d3;
            }
            __syncthreads();
        }
    }

    // MLP
    {
        const int f = tid;
        float h0 = 0, h1 = 0, h2 = 0, h3 = 0;
        #pragma unroll 8
        for (int d = 0; d < 64; d++) {
            float  w = W1[d * 256 + f];                      // 256B coalesced, L2-hot
            float4 c = *(const float4*)(caps4 + d * 4);
            h0 = fmaf(c.x, w, h0);
            h1 = fmaf(c.y, w, h1);
            h2 = fmaf(c.z, w, h2);
            h3 = fmaf(c.w, w, h3);
        }
        float bb = b1[f];
        h0 = fmaxf(h0 + bb, 0.f);
        h1 = fmaxf(h1 + bb, 0.f);
        h2 = fmaxf(h2 + bb, 0.f);
        h3 = fmaxf(h3 + bb, 0.f);
        h4[f * 4 + 0] = h0; h4[f * 4 + 1] = h1;
        h4[f * 4 + 2] = h2; h4[f * 4 + 3] = h3;
    }
    __syncthreads();
    {
        // out partials: q = wv covers f in [q*64, q*64+64), d = lane
        float o0 = 0, o1 = 0, o2 = 0, o3 = 0;
        #pragma unroll 8
        for (int i = 0; i < 64; i++) {
            int f = wv * 64 + i;
            float  w  = W2[f * 64 + lane];                   // 256B coalesced, L2-hot
            float4 hv = *(const float4*)(h4 + f * 4);        // broadcast b128
            o0 = fmaf(hv.x, w, o0);
            o1 = fmaf(hv.y, w, o1);
            o2 = fmaf(hv.z, w, o2);
            o3 = fmaf(hv.w, w, o3);
        }
        part[wv * 256 + lane]       = o0;
        part[wv * 256 + 64 + lane]  = o1;
        part[wv * 256 + 128 + lane] = o2;
        part[wv * 256 + 192 + lane] = o3;
    }
    __syncthreads();
    {
        float o = part[wv * 64 + lane]       + part[256 + wv * 64 + lane]
                + part[512 + wv * 64 + lane] + part[768 + wv * 64 + lane];
        out[b * 256 + tid] = o + b2[lane];   // (b, k=wv, d=lane) contiguous
    }
}

extern "C" void kernel_launch(void* const* d_in, const int* in_sizes, int n_in,
                              void* d_out, int out_size, void* d_ws, size_t ws_size,
                              hipStream_t stream) {
    const int*   his = (const int*)  d_in[0];
    const float* E   = (const float*)d_in[1];
    const float* S   = (const float*)d_in[2];
    const float* B0  = (const float*)d_in[3];
    const float* W1  = (const float*)d_in[4];
    const float* b1  = (const float*)d_in[5];
    const float* W2  = (const float*)d_in[6];
    const float* b2  = (const float*)d_in[7];
    float* out = (float*)d_out;
    float* P   = (float*)d_ws;            // NVOC*64 floats = 25.6 MB scratch

    precompute_P<<<1024, 256, 0, stream>>>(E, S, P);
    mind_row<<<4096, 256, 0, stream>>>(his, P, B0, W1, b1, W2, b2, out);
}

// Round 5
// 224.676 us; speedup vs baseline: 1.1123x; 1.1123x over previous
//
#include <hip/hip_runtime.h>

#define LSEQ 200
#define KCAP 4
#define NVOC 100000

// ---------------------------------------------------------------------------
// Kernel 1: P = (E with row 0 zeroed) @ S, P: (NVOC, 64) in workspace.
// Verbatim round-0 version (passed). 16 vocab rows per block; thread
// computes 4 rows x 1 col via transposed E-tile in LDS + S in LDS.
// ---------------------------------------------------------------------------
__global__ __launch_bounds__(256) void precompute_P(
    const float* __restrict__ E, const float* __restrict__ S,
    float* __restrict__ P)
{
    __shared__ __align__(16) float Sl[64 * 64];
    __shared__ __align__(16) float Et[64 * 16];   // Et[e*16 + r] = E[(vbase+r)*64 + e]
    const int tid = threadIdx.x;
    #pragma unroll
    for (int t = tid; t < 4096; t += 256) Sl[t] = S[t];
    const int vbase = blockIdx.x * 16;
    #pragma unroll
    for (int t = tid; t < 1024; t += 256) {
        int r = t >> 6, e = t & 63;
        Et[e * 16 + r] = E[(vbase + r) * 64 + e];
    }
    __syncthreads();
    const int d = tid & 63, q = tid >> 6;
    float a0 = 0.f, a1 = 0.f, a2 = 0.f, a3 = 0.f;
    #pragma unroll
    for (int e = 0; e < 64; e++) {
        float4 ev = *(const float4*)(Et + e * 16 + q * 4);  // broadcast b128
        float  s  = Sl[e * 64 + d];                          // 2-way bank: free
        a0 = fmaf(ev.x, s, a0);
        a1 = fmaf(ev.y, s, a1);
        a2 = fmaf(ev.z, s, a2);
        a3 = fmaf(ev.w, s, a3);
    }
    const int v0 = vbase + q * 4;
    if (v0 == 0) a0 = 0.f;               // padding_idx=0 -> P row 0 is zero
    P[(v0 + 0) * 64 + d] = a0;
    P[(v0 + 1) * 64 + d] = a1;
    P[(v0 + 2) * 64 + d] = a2;
    P[(v0 + 3) * 64 + d] = a3;
}

// ---------------------------------------------------------------------------
// Kernel 2: one batch row per block (256 threads = 4 waves).
// Merge of the two PASSING kernels' components only:
//   phases A/B/C/D/MLP verbatim from round 1 (absmax 4.88e-4);
//   phase D reads its hisP row from global P (L1/L2-hot after the gather) —
//   the LDS-transpose variant (rounds 2-4) is abandoned: its within-wave
//   scalar-write -> float4-read with no fence failed 3x.
// Fixes vs round 1 (perf only, not arithmetic):
//   - __launch_bounds__(256,4): 128-VGPR budget -> hp[50] stays in registers
//     (round 1's (256,5) gave VGPR=48 + 70 MB scratch writeback).
//   - pooled LDS 17344 B (no 52 KB hisPl) -> 4 blocks/CU.
//
// LDS pool (floats), offsets verified non-overlapping:
//   Bm    [0    .. 832)   [k*208 + l]; pad l=200..207 unread
//   W4    [832  .. 1632)  [l*4 + k]   (16B-aligned float4 reads)
//   caps4 [1632 .. 1888)  [d*4 + k]   (16B-aligned float4 broadcast)
//   bigneg[1888 .. 2088)
//   idxs  [2088 .. 2288)  int[200], live for phase D -> NOT in the union
//   SC    [2288 .. 4336)  union: part[1024] | h4 = SC+1024 (16B-aligned)
// ---------------------------------------------------------------------------
__global__ __launch_bounds__(256, 4) void mind_row(
    const int*   __restrict__ his, const float* __restrict__ P,
    const float* __restrict__ B0,  const float* __restrict__ W1,
    const float* __restrict__ b1,  const float* __restrict__ W2,
    const float* __restrict__ b2,  float* __restrict__ out)
{
    __shared__ __align__(16) float POOL[4336];
    float* Bm     = POOL;          // [k*208 + l]
    float* W4     = POOL + 832;    // [l*4 + k]
    float* caps4  = POOL + 1632;   // [d*4 + k]
    float* bigneg = POOL + 1888;   // [200]
    int*   idxs   = (int*)(POOL + 2088);   // [200], live whole kernel
    float* SC     = POOL + 2288;   // 2048-float union
    float* part   = SC;            // [q*256 + k*64 + d]  (phase B -> C; MLP2)
    float* h4     = SC + 1024;     // [f*4 + k]           (MLP)

    const int b    = blockIdx.x;
    const int tid  = threadIdx.x;
    const int lane = tid & 63;
    const int wv   = tid >> 6;

    // ---- setup -------------------------------------------------------------
    for (int l = tid; l < LSEQ; l += 256) {
        int id = his[b * LSEQ + l];
        idxs[l]   = id;
        bigneg[l] = (id != 0) ? 0.f : -1e30f;
    }
    if (tid < LSEQ) {
        #pragma unroll
        for (int k = 0; k < KCAP; k++) Bm[k * 208 + tid] = B0[k * LSEQ + tid];
    }
    __syncthreads();

    // ---- gather hisP rows: wave covers l in [wv*50, wv*50+50), lane = d ----
    float hp[50];
    #pragma unroll
    for (int i = 0; i < 50; i++) {
        int l = wv * 50 + i;
        hp[i] = P[idxs[l] * 64 + lane];     // 256B coalesced per wave; row0=0
    }

    for (int r = 0; r < 3; r++) {
        // A: masked softmax over l, capsule k = wv (one wave per capsule)
        {
            const float* Bk = Bm + wv * 208;
            float x0 = Bk[lane]       + bigneg[lane];
            float x1 = Bk[lane + 64]  + bigneg[lane + 64];
            float x2 = Bk[lane + 128] + bigneg[lane + 128];
            float x3 = (lane < 8) ? (Bk[lane + 192] + bigneg[lane + 192]) : -3.0e38f;
            float m = fmaxf(fmaxf(x0, x1), fmaxf(x2, x3));
            #pragma unroll
            for (int off = 32; off; off >>= 1) m = fmaxf(m, __shfl_xor(m, off, 64));
            float e0 = __expf(x0 - m), e1 = __expf(x1 - m), e2 = __expf(x2 - m);
            float e3 = (lane < 8) ? __expf(x3 - m) : 0.f;
            float ssum = e0 + e1 + e2 + e3;
            #pragma unroll
            for (int off = 32; off; off >>= 1) ssum += __shfl_xor(ssum, off, 64);
            float inv = 1.f / ssum;
            W4[lane * 4 + wv]         = e0 * inv;
            W4[(lane + 64) * 4 + wv]  = e1 * inv;
            W4[(lane + 128) * 4 + wv] = e2 * inv;
            if (lane < 8) W4[(lane + 192) * 4 + wv] = e3 * inv;
        }
        __syncthreads();

        // B: caps partials from register-resident hisP (exact ref summands)
        {
            float a0 = 0, a1 = 0, a2 = 0, a3 = 0;
            #pragma unroll
            for (int i = 0; i < 50; i++) {
                int l = wv * 50 + i;
                float4 w = *(const float4*)(W4 + l * 4);   // broadcast b128
                float  v = hp[i];
                a0 = fmaf(w.x, v, a0);
                a1 = fmaf(w.y, v, a1);
                a2 = fmaf(w.z, v, a2);
                a3 = fmaf(w.w, v, a3);
            }
            part[wv * 256 + lane]       = a0;
            part[wv * 256 + 64 + lane]  = a1;
            part[wv * 256 + 128 + lane] = a2;
            part[wv * 256 + 192 + lane] = a3;
        }
        __syncthreads();

        // C: reduce partials + squash; thread = (k = wv, d = lane)
        {
            float c = part[wv * 64 + lane]       + part[256 + wv * 64 + lane]
                    + part[512 + wv * 64 + lane] + part[768 + wv * 64 + lane];
            float n2 = c * c;
            #pragma unroll
            for (int off = 32; off; off >>= 1) n2 += __shfl_xor(n2, off, 64);
            float n  = sqrtf(n2);
            float sc = n2 / ((1.f + n2) * n + 1e-9f);
            c *= sc;
            caps4[lane * 4 + wv] = c;
        }
        __syncthreads();

        if (r < 2) {
            // D: B[k][l] += caps[k] . hisP[l]  (thread per l; verbatim from
            // the passing round-1 kernel). hisP row re-read from global P:
            // the block just gathered these rows -> L1/L2-hot. d ascending ->
            // bit-identical sum to the reference association.
            if (tid < LSEQ) {
                const float4* __restrict__ rowp = (const float4*)(P + idxs[tid] * 64);
                float d0 = 0, d1 = 0, d2 = 0, d3 = 0;
                #pragma unroll
                for (int j = 0; j < 16; j++) {
                    float4 v = rowp[j];
                    {
                        float4 c = *(const float4*)(caps4 + (j * 4 + 0) * 4);
                        d0 = fmaf(c.x, v.x, d0); d1 = fmaf(c.y, v.x, d1);
                        d2 = fmaf(c.z, v.x, d2); d3 = fmaf(c.w, v.x, d3);
                    }
                    {
                        float4 c = *(const float4*)(caps4 + (j * 4 + 1) * 4);
                        d0 = fmaf(c.x, v.y, d0); d1 = fmaf(c.y, v.y, d1);
                        d2 = fmaf(c.z, v.y, d2); d3 = fmaf(c.w, v.y, d3);
                    }
                    {
                        float4 c = *(const float4*)(caps4 + (j * 4 + 2) * 4);
                        d0 = fmaf(c.x, v.z, d0); d1 = fmaf(c.y, v.z, d1);
                        d2 = fmaf(c.z, v.z, d2); d3 = fmaf(c.w, v.z, d3);
                    }
                    {
                        float4 c = *(const float4*)(caps4 + (j * 4 + 3) * 4);
                        d0 = fmaf(c.x, v.w, d0); d1 = fmaf(c.y, v.w, d1);
                        d2 = fmaf(c.z, v.w, d2); d3 = fmaf(c.w, v.w, d3);
                    }
                }
                Bm[tid]       += d0;
                Bm[208 + tid] += d1;
                Bm[416 + tid] += d2;
                Bm[624 + tid] += d3;
            }
            __syncthreads();
        }
    }

    // MLP layer 1: h = relu(caps @ W1 + b1), h4[f*4+k]
    {
        const int f = tid;
        float h0 = 0, h1 = 0, h2 = 0, h3 = 0;
        #pragma unroll 8
        for (int d = 0; d < 64; d++) {
            float  w = W1[d * 256 + f];                      // coalesced, L2-hot
            float4 c = *(const float4*)(caps4 + d * 4);
            h0 = fmaf(c.x, w, h0);
            h1 = fmaf(c.y, w, h1);
            h2 = fmaf(c.z, w, h2);
            h3 = fmaf(c.w, w, h3);
        }
        float bb = b1[f];
        h0 = fmaxf(h0 + bb, 0.f);
        h1 = fmaxf(h1 + bb, 0.f);
        h2 = fmaxf(h2 + bb, 0.f);
        h3 = fmaxf(h3 + bb, 0.f);
        h4[f * 4 + 0] = h0; h4[f * 4 + 1] = h1;
        h4[f * 4 + 2] = h2; h4[f * 4 + 3] = h3;
    }
    __syncthreads();

    // MLP layer 2 partials: q = wv covers f in [q*64, q*64+64), d = lane
    {
        float o0 = 0, o1 = 0, o2 = 0, o3 = 0;
        #pragma unroll 8
        for (int i = 0; i < 64; i++) {
            int f = wv * 64 + i;
            float  w  = W2[f * 64 + lane];                   // coalesced, L2-hot
            float4 hv = *(const float4*)(h4 + f * 4);        // broadcast b128
            o0 = fmaf(hv.x, w, o0);
            o1 = fmaf(hv.y, w, o1);
            o2 = fmaf(hv.z, w, o2);
            o3 = fmaf(hv.w, w, o3);
        }
        part[wv * 256 + lane]       = o0;
        part[wv * 256 + 64 + lane]  = o1;
        part[wv * 256 + 128 + lane] = o2;
        part[wv * 256 + 192 + lane] = o3;
    }
    __syncthreads();
    {
        float o = part[wv * 64 + lane]       + part[256 + wv * 64 + lane]
                + part[512 + wv * 64 + lane] + part[768 + wv * 64 + lane];
        out[b * 256 + tid] = o + b2[lane];   // (b, k=wv, d=lane) contiguous
    }
}

extern "C" void kernel_launch(void* const* d_in, const int* in_sizes, int n_in,
                              void* d_out, int out_size, void* d_ws, size_t ws_size,
                              hipStream_t stream) {
    const int*   his = (const int*)  d_in[0];
    const float* E   = (const float*)d_in[1];
    const float* S   = (const float*)d_in[2];
    const float* B0  = (const float*)d_in[3];
    const float* W1  = (const float*)d_in[4];
    const float* b1  = (const float*)d_in[5];
    const float* W2  = (const float*)d_in[6];
    const float* b2  = (const float*)d_in[7];
    float* out = (float*)d_out;
    float* P   = (float*)d_ws;            // NVOC*64 floats = 25.6 MB scratch

    precompute_P<<<NVOC / 16, 256, 0, stream>>>(E, S, P);
    mind_row<<<4096, 256, 0, stream>>>(his, P, B0, W1, b1, W2, b2, out);
}

// Round 6
// 221.695 us; speedup vs baseline: 1.1273x; 1.0134x over previous
//
#include <hip/hip_runtime.h>

#define LSEQ 200
#define KCAP 4
#define NVOC 100000

// ---------------------------------------------------------------------------
// Kernel 1: P = (E with row 0 zeroed) @ S, P: (NVOC, 64) in workspace.
// v3: register-tiled GEMM. 64 vocab rows x 64 cols per block (1563 blocks),
// 4x4 per-thread tile: per e-step 2x ds_read_b128 feed 16 FMAs (4x the
// FMA/LDS ratio of the 16-row version, 4x fewer S re-stagings).
//   Et stride 68: staging write banks (4e+r)%32 (benign, 16 wave-instrs);
//     b128 read = 16 distinct dwords, broadcast, conflict-free.
//   Sl stride 64: b128 read = 64 dwords -> 2-way = free.
// Each acc[i][j] is one fmaf chain over e ascending -> P bit-identical to
// the round-0/5 version (mind_row numerics untouched).
// ---------------------------------------------------------------------------
__global__ __launch_bounds__(256) void precompute_P(
    const float* __restrict__ E, const float* __restrict__ S,
    float* __restrict__ P)
{
    __shared__ __align__(16) float Sl[64 * 64];   // Sl[e*64 + d]
    __shared__ __align__(16) float Et[64 * 68];   // Et[e*68 + r] = E[(vbase+r)*64+e]
    const int tid   = threadIdx.x;
    const int vbase = blockIdx.x * 64;

    #pragma unroll
    for (int t = tid; t < 4096; t += 256) Sl[t] = S[t];
    #pragma unroll
    for (int t = tid; t < 4096; t += 256) {
        int r = t >> 6, e = t & 63;               // wave: r fixed, e=lane -> coalesced
        int v = vbase + r;
        Et[e * 68 + r] = (v < NVOC) ? E[v * 64 + e] : 0.f;
    }
    __syncthreads();

    const int rq = tid >> 4;                      // 16 row-quads
    const int cq = tid & 15;                      // 16 col-quads
    float a00=0,a01=0,a02=0,a03=0, a10=0,a11=0,a12=0,a13=0;
    float a20=0,a21=0,a22=0,a23=0, a30=0,a31=0,a32=0,a33=0;
    #pragma unroll 8
    for (int e = 0; e < 64; e++) {
        float4 ev = *(const float4*)(Et + e * 68 + rq * 4);
        float4 sv = *(const float4*)(Sl + e * 64 + cq * 4);
        a00 = fmaf(ev.x, sv.x, a00); a01 = fmaf(ev.x, sv.y, a01);
        a02 = fmaf(ev.x, sv.z, a02); a03 = fmaf(ev.x, sv.w, a03);
        a10 = fmaf(ev.y, sv.x, a10); a11 = fmaf(ev.y, sv.y, a11);
        a12 = fmaf(ev.y, sv.z, a12); a13 = fmaf(ev.y, sv.w, a13);
        a20 = fmaf(ev.z, sv.x, a20); a21 = fmaf(ev.z, sv.y, a21);
        a22 = fmaf(ev.z, sv.z, a22); a23 = fmaf(ev.z, sv.w, a23);
        a30 = fmaf(ev.w, sv.x, a30); a31 = fmaf(ev.w, sv.y, a31);
        a32 = fmaf(ev.w, sv.z, a32); a33 = fmaf(ev.w, sv.w, a33);
    }

    const int r0 = vbase + rq * 4;
    float4 o0 = make_float4(a00, a01, a02, a03);
    float4 o1 = make_float4(a10, a11, a12, a13);
    float4 o2 = make_float4(a20, a21, a22, a23);
    float4 o3 = make_float4(a30, a31, a32, a33);
    if (r0 == 0) o0 = make_float4(0.f, 0.f, 0.f, 0.f);  // padding_idx=0
    if (r0 + 0 < NVOC) *(float4*)(P + (r0 + 0) * 64 + cq * 4) = o0;
    if (r0 + 1 < NVOC) *(float4*)(P + (r0 + 1) * 64 + cq * 4) = o1;
    if (r0 + 2 < NVOC) *(float4*)(P + (r0 + 2) * 64 + cq * 4) = o2;
    if (r0 + 3 < NVOC) *(float4*)(P + (r0 + 3) * 64 + cq * 4) = o3;
}

// ---------------------------------------------------------------------------
// Kernel 2: one batch row per block (256 threads = 4 waves).
// VERBATIM from the passing round-5 kernel (absmax 4.88e-4). Do not touch.
// ---------------------------------------------------------------------------
__global__ __launch_bounds__(256, 4) void mind_row(
    const int*   __restrict__ his, const float* __restrict__ P,
    const float* __restrict__ B0,  const float* __restrict__ W1,
    const float* __restrict__ b1,  const float* __restrict__ W2,
    const float* __restrict__ b2,  float* __restrict__ out)
{
    __shared__ __align__(16) float POOL[4336];
    float* Bm     = POOL;          // [k*208 + l]
    float* W4     = POOL + 832;    // [l*4 + k]
    float* caps4  = POOL + 1632;   // [d*4 + k]
    float* bigneg = POOL + 1888;   // [200]
    int*   idxs   = (int*)(POOL + 2088);   // [200], live whole kernel
    float* SC     = POOL + 2288;   // 2048-float union
    float* part   = SC;            // [q*256 + k*64 + d]  (phase B -> C; MLP2)
    float* h4     = SC + 1024;     // [f*4 + k]           (MLP)

    const int b    = blockIdx.x;
    const int tid  = threadIdx.x;
    const int lane = tid & 63;
    const int wv   = tid >> 6;

    // ---- setup -------------------------------------------------------------
    for (int l = tid; l < LSEQ; l += 256) {
        int id = his[b * LSEQ + l];
        idxs[l]   = id;
        bigneg[l] = (id != 0) ? 0.f : -1e30f;
    }
    if (tid < LSEQ) {
        #pragma unroll
        for (int k = 0; k < KCAP; k++) Bm[k * 208 + tid] = B0[k * LSEQ + tid];
    }
    __syncthreads();

    // ---- gather hisP rows: wave covers l in [wv*50, wv*50+50), lane = d ----
    float hp[50];
    #pragma unroll
    for (int i = 0; i < 50; i++) {
        int l = wv * 50 + i;
        hp[i] = P[idxs[l] * 64 + lane];     // 256B coalesced per wave; row0=0
    }

    for (int r = 0; r < 3; r++) {
        // A: masked softmax over l, capsule k = wv (one wave per capsule)
        {
            const float* Bk = Bm + wv * 208;
            float x0 = Bk[lane]       + bigneg[lane];
            float x1 = Bk[lane + 64]  + bigneg[lane + 64];
            float x2 = Bk[lane + 128] + bigneg[lane + 128];
            float x3 = (lane < 8) ? (Bk[lane + 192] + bigneg[lane + 192]) : -3.0e38f;
            float m = fmaxf(fmaxf(x0, x1), fmaxf(x2, x3));
            #pragma unroll
            for (int off = 32; off; off >>= 1) m = fmaxf(m, __shfl_xor(m, off, 64));
            float e0 = __expf(x0 - m), e1 = __expf(x1 - m), e2 = __expf(x2 - m);
            float e3 = (lane < 8) ? __expf(x3 - m) : 0.f;
            float ssum = e0 + e1 + e2 + e3;
            #pragma unroll
            for (int off = 32; off; off >>= 1) ssum += __shfl_xor(ssum, off, 64);
            float inv = 1.f / ssum;
            W4[lane * 4 + wv]         = e0 * inv;
            W4[(lane + 64) * 4 + wv]  = e1 * inv;
            W4[(lane + 128) * 4 + wv] = e2 * inv;
            if (lane < 8) W4[(lane + 192) * 4 + wv] = e3 * inv;
        }
        __syncthreads();

        // B: caps partials from register-resident hisP (exact ref summands)
        {
            float a0 = 0, a1 = 0, a2 = 0, a3 = 0;
            #pragma unroll
            for (int i = 0; i < 50; i++) {
                int l = wv * 50 + i;
                float4 w = *(const float4*)(W4 + l * 4);   // broadcast b128
                float  v = hp[i];
                a0 = fmaf(w.x, v, a0);
                a1 = fmaf(w.y, v, a1);
                a2 = fmaf(w.z, v, a2);
                a3 = fmaf(w.w, v, a3);
            }
            part[wv * 256 + lane]       = a0;
            part[wv * 256 + 64 + lane]  = a1;
            part[wv * 256 + 128 + lane] = a2;
            part[wv * 256 + 192 + lane] = a3;
        }
        __syncthreads();

        // C: reduce partials + squash; thread = (k = wv, d = lane)
        {
            float c = part[wv * 64 + lane]       + part[256 + wv * 64 + lane]
                    + part[512 + wv * 64 + lane] + part[768 + wv * 64 + lane];
            float n2 = c * c;
            #pragma unroll
            for (int off = 32; off; off >>= 1) n2 += __shfl_xor(n2, off, 64);
            float n  = sqrtf(n2);
            float sc = n2 / ((1.f + n2) * n + 1e-9f);
            c *= sc;
            caps4[lane * 4 + wv] = c;
        }
        __syncthreads();

        if (r < 2) {
            // D: B[k][l] += caps[k] . hisP[l]  (thread per l). hisP row
            // re-read from global P (L1/L2-hot). d ascending -> bit-identical.
            if (tid < LSEQ) {
                const float4* __restrict__ rowp = (const float4*)(P + idxs[tid] * 64);
                float d0 = 0, d1 = 0, d2 = 0, d3 = 0;
                #pragma unroll
                for (int j = 0; j < 16; j++) {
                    float4 v = rowp[j];
                    {
                        float4 c = *(const float4*)(caps4 + (j * 4 + 0) * 4);
                        d0 = fmaf(c.x, v.x, d0); d1 = fmaf(c.y, v.x, d1);
                        d2 = fmaf(c.z, v.x, d2); d3 = fmaf(c.w, v.x, d3);
                    }
                    {
                        float4 c = *(const float4*)(caps4 + (j * 4 + 1) * 4);
                        d0 = fmaf(c.x, v.y, d0); d1 = fmaf(c.y, v.y, d1);
                        d2 = fmaf(c.z, v.y, d2); d3 = fmaf(c.w, v.y, d3);
                    }
                    {
                        float4 c = *(const float4*)(caps4 + (j * 4 + 2) * 4);
                        d0 = fmaf(c.x, v.z, d0); d1 = fmaf(c.y, v.z, d1);
                        d2 = fmaf(c.z, v.z, d2); d3 = fmaf(c.w, v.z, d3);
                    }
                    {
                        float4 c = *(const float4*)(caps4 + (j * 4 + 3) * 4);
                        d0 = fmaf(c.x, v.w, d0); d1 = fmaf(c.y, v.w, d1);
                        d2 = fmaf(c.z, v.w, d2); d3 = fmaf(c.w, v.w, d3);
                    }
                }
                Bm[tid]       += d0;
                Bm[208 + tid] += d1;
                Bm[416 + tid] += d2;
                Bm[624 + tid] += d3;
            }
            __syncthreads();
        }
    }

    // MLP layer 1: h = relu(caps @ W1 + b1), h4[f*4+k]
    {
        const int f = tid;
        float h0 = 0, h1 = 0, h2 = 0, h3 = 0;
        #pragma unroll 8
        for (int d = 0; d < 64; d++) {
            float  w = W1[d * 256 + f];                      // coalesced, L2-hot
            float4 c = *(const float4*)(caps4 + d * 4);
            h0 = fmaf(c.x, w, h0);
            h1 = fmaf(c.y, w, h1);
            h2 = fmaf(c.z, w, h2);
            h3 = fmaf(c.w, w, h3);
        }
        float bb = b1[f];
        h0 = fmaxf(h0 + bb, 0.f);
        h1 = fmaxf(h1 + bb, 0.f);
        h2 = fmaxf(h2 + bb, 0.f);
        h3 = fmaxf(h3 + bb, 0.f);
        h4[f * 4 + 0] = h0; h4[f * 4 + 1] = h1;
        h4[f * 4 + 2] = h2; h4[f * 4 + 3] = h3;
    }
    __syncthreads();

    // MLP layer 2 partials: q = wv covers f in [q*64, q*64+64), d = lane
    {
        float o0 = 0, o1 = 0, o2 = 0, o3 = 0;
        #pragma unroll 8
        for (int i = 0; i < 64; i++) {
            int f = wv * 64 + i;
            float  w  = W2[f * 64 + lane];                   // coalesced, L2-hot
            float4 hv = *(const float4*)(h4 + f * 4);        // broadcast b128
            o0 = fmaf(hv.x, w, o0);
            o1 = fmaf(hv.y, w, o1);
            o2 = fmaf(hv.z, w, o2);
            o3 = fmaf(hv.w, w, o3);
        }
        part[wv * 256 + lane]       = o0;
        part[wv * 256 + 64 + lane]  = o1;
        part[wv * 256 + 128 + lane] = o2;
        part[wv * 256 + 192 + lane] = o3;
    }
    __syncthreads();
    {
        float o = part[wv * 64 + lane]       + part[256 + wv * 64 + lane]
                + part[512 + wv * 64 + lane] + part[768 + wv * 64 + lane];
        out[b * 256 + tid] = o + b2[lane];   // (b, k=wv, d=lane) contiguous
    }
}

extern "C" void kernel_launch(void* const* d_in, const int* in_sizes, int n_in,
                              void* d_out, int out_size, void* d_ws, size_t ws_size,
                              hipStream_t stream) {
    const int*   his = (const int*)  d_in[0];
    const float* E   = (const float*)d_in[1];
    const float* S   = (const float*)d_in[2];
    const float* B0  = (const float*)d_in[3];
    const float* W1  = (const float*)d_in[4];
    const float* b1  = (const float*)d_in[5];
    const float* W2  = (const float*)d_in[6];
    const float* b2  = (const float*)d_in[7];
    float* out = (float*)d_out;
    float* P   = (float*)d_ws;            // NVOC*64 floats = 25.6 MB scratch

    precompute_P<<<(NVOC + 63) / 64, 256, 0, stream>>>(E, S, P);
    mind_row<<<4096, 256, 0, stream>>>(his, P, B0, W1, b1, W2, b2, out);
}